// Round 4
// baseline (474.751 us; speedup 1.0000x reference)
//
#include <hip/hip_runtime.h>
#include <cstdint>
#include <cstddef>

typedef int i32x4 __attribute__((ext_vector_type(4)));

#define BM 256
#define BN 256
#define BK 64   // bytes of K per tile; one mfma_i32_16x16x64_i8 covers the whole tile-K

__device__ __forceinline__ void load16_to_lds(const void* g, void* l) {
  __builtin_amdgcn_global_load_lds(
      (const __attribute__((address_space(1))) void*)g,
      (__attribute__((address_space(3))) void*)l,
      16, 0, 0);
}

// Fused input quantization.
// Blocks [0, M): per-row absmax + int8 quantize of x (row held in regs).
// Blocks [M, M + N*K/4096): pack int32 weights (values in [-127,127]) to int8.
__global__ __launch_bounds__(256) void quant_xw(const float* __restrict__ x,
                                                char* __restrict__ xq,
                                                float* __restrict__ sx,
                                                const int* __restrict__ w,
                                                char* __restrict__ wq,
                                                int M, int K) {
  const int t = threadIdx.x;
  __shared__ float red[4];
  if ((int)blockIdx.x < M) {
    const int row = blockIdx.x;
    const float* xr = x + (size_t)row * K;
    float4 v[4];
    float amax = 0.f;
#pragma unroll
    for (int j = 0; j < 4; ++j) {
      v[j] = ((const float4*)xr)[t + j * 256];
      amax = fmaxf(amax, fmaxf(fmaxf(fabsf(v[j].x), fabsf(v[j].y)),
                               fmaxf(fabsf(v[j].z), fabsf(v[j].w))));
    }
#pragma unroll
    for (int off = 32; off; off >>= 1)
      amax = fmaxf(amax, __shfl_xor(amax, off));
    if ((t & 63) == 0) red[t >> 6] = amax;
    __syncthreads();
    amax = fmaxf(fmaxf(red[0], red[1]), fmaxf(red[2], red[3]));
    amax = fmaxf(amax, 1e-20f);

    const float s = 127.0f / amax;
    int* outw = (int*)(xq + (size_t)row * K);
#pragma unroll
    for (int j = 0; j < 4; ++j) {
      int q0 = __float2int_rn(v[j].x * s);
      int q1 = __float2int_rn(v[j].y * s);
      int q2 = __float2int_rn(v[j].z * s);
      int q3 = __float2int_rn(v[j].w * s);
      int pk = (q0 & 0xff) | ((q1 & 0xff) << 8) | ((q2 & 0xff) << 16) | ((q3 & 0xff) << 24);
      outw[t + j * 256] = pk;
    }
    if (t == 0) sx[row] = amax * (1.0f / 127.0f);
  } else {
    const size_t base = (size_t)(blockIdx.x - M) * 4096;
    int* outw = (int*)(wq + base);
#pragma unroll
    for (int j = 0; j < 4; ++j) {
      const int c = t + j * 256;
      int4 a = ((const int4*)(w + base))[c];
      outw[c] = (a.x & 0xff) | ((a.y & 0xff) << 8) | ((a.z & 0xff) << 16) | ((a.w & 0xff) << 24);
    }
  }
}

// C[m][n] = sum_k A[m][k]*Bw[n][k] (int8 -> int32); out = C*sx[m]*sw[n] + bias[n].
// 256x256 tile, 512 thr (8 waves: 2M x 4N), BK=64B, mfma_i32_16x16x64_i8.
// Round-1 barrier cadence (2 phases x 16 MFMA, 4 barriers/tile) + FULL one-phase-ahead
// ds_read pipelining: no phase starts with an exposed read chain.
//   P0(t): stage A(t+2); issue part2(t)={a4..7}; bar; MFMA16{a0-3 x b0-3}; bar
//   P1(t): stage B(t+2); vmcnt(4); issue part1(t+1)={a0-3,b0-3}; bar;
//          MFMA16{a4-7 x b0-3}; bar
// lgkm waits: compiler-inserted counted waits (reads are compiler-visible; m97-precise).
// vmcnt FIFO: entering tile t, outstanding = [A(t+1),B(t+1)] (4). P0 +A(t+2)=6,
// P1 +B(t+2)=8; vmcnt(4) retires A(t+1),B(t+1) -> part1(t+1) reads safe.
// WAR: DMA into (t+2)%3==(t-1)%3 after that buffer's last reads (part2(t-1)) completed
// (lgkm-waited before t-1 P1 MFMA, which precedes the interposed barriers).
// LDS swizzle (verified conflict-free): 16B chunk (row r, chunk c) at byte
// r*64 + ((c^((r>>1)&3))<<4); staged via pre-swizzled global source, linear DMA dst.
__global__ __launch_bounds__(512) void gemm_i8_bt(const char* __restrict__ A,
                                                  const char* __restrict__ Bw,
                                                  const float* __restrict__ sx,
                                                  const float* __restrict__ sw,
                                                  const float* __restrict__ bias,
                                                  float* __restrict__ out,
                                                  int M, int N, int K) {
  __shared__ __align__(16) char As[3][BM * BK];   // 3 x 16 KiB
  __shared__ __align__(16) char Bs[3][BN * BK];   // 3 x 16 KiB  (96 KiB total)

  const int tid  = threadIdx.x;
  const int wave = tid >> 6;
  const int lane = tid & 63;
  const int wm   = wave >> 2;      // 0..1 -> 128-row half
  const int wn   = wave & 3;       // 0..3 -> 64-col quarter

  // XCD-aware bijective block swizzle (nwg = 512, divisible by 8)
  const int gx   = N / BN;                              // 16
  const int nwg  = gx * (M / BM);                       // 512
  const int orig = blockIdx.y * gx + blockIdx.x;
  const int wg   = (orig & 7) * (nwg >> 3) + (orig >> 3);
  const int bn   = wg % gx;
  const int bm   = wg / gx;

  i32x4 acc[8][4] = {};

  // Staging: thread stages 16B chunks q=tid and q=tid+512 of each tile.
  // LDS chunk position p=q&3 of row q>>2 holds global chunk p ^ ((row>>1)&3).
  const int rowT = tid >> 2;
  const int jg   = ((tid & 3) ^ ((tid >> 3) & 3)) << 4;
  const char* Ag1 = A  + (size_t)(bm * BM + rowT) * K + jg;
  const char* Ag2 = Ag1 + (size_t)128 * K;
  const char* Bg1 = Bw + (size_t)(bn * BN + rowT) * K + jg;
  const char* Bg2 = Bg1 + (size_t)128 * K;

  const int ldsO1 = wave << 10;             // chunk q=tid      -> byte tid*16
  const int ldsO2 = 8192 + (wave << 10);    // chunk q=tid+512

  // Fragment read offsets: row R, k-chunk j=lane>>4 at byte R*64 + ((j^((R>>1)&3))<<4).
  const int fr  = lane & 15;
  const int swz = (((lane >> 4) ^ ((fr >> 1) & 3)) << 4);
  int offA[8], offB[4];
#pragma unroll
  for (int m = 0; m < 8; ++m) offA[m] = (wm * 128 + m * 16 + fr) * 64 + swz;
#pragma unroll
  for (int n = 0; n < 4; ++n) offB[n] = (wn * 64 + n * 16 + fr) * 64 + swz;

  const int NT = K / BK;    // 64

  // Prologue: stage tiles 0,1; retire tile 0's 4 loads (keep tile 1's in flight).
  load16_to_lds(Ag1,      &As[0][ldsO1]);
  load16_to_lds(Ag2,      &As[0][ldsO2]);
  load16_to_lds(Bg1,      &Bs[0][ldsO1]);
  load16_to_lds(Bg2,      &Bs[0][ldsO2]);
  load16_to_lds(Ag1 + BK, &As[1][ldsO1]);
  load16_to_lds(Ag2 + BK, &As[1][ldsO2]);
  load16_to_lds(Bg1 + BK, &Bs[1][ldsO1]);
  load16_to_lds(Bg2 + BK, &Bs[1][ldsO2]);
  asm volatile("s_waitcnt vmcnt(4)" ::: "memory");
  __builtin_amdgcn_s_barrier();
  __builtin_amdgcn_sched_barrier(0);

  // part1(0): issued before the loop; consumed by tile 0 P0's MFMA cluster.
  i32x4 ca0 = *(const i32x4*)&As[0][offA[0]];
  i32x4 ca1 = *(const i32x4*)&As[0][offA[1]];
  i32x4 ca2 = *(const i32x4*)&As[0][offA[2]];
  i32x4 ca3 = *(const i32x4*)&As[0][offA[3]];
  i32x4 cb0 = *(const i32x4*)&Bs[0][offB[0]];
  i32x4 cb1 = *(const i32x4*)&Bs[0][offB[1]];
  i32x4 cb2 = *(const i32x4*)&Bs[0][offB[2]];
  i32x4 cb3 = *(const i32x4*)&Bs[0][offB[3]];

  int buf = 0;                              // tile t lives in buffer t % 3
  for (int t = 0; t < NT; ++t) {
    const int  nb = (buf >= 1) ? buf - 1 : 2;      // (t+2) % 3
    const int  nx = (buf < 2) ? buf + 1 : 0;       // (t+1) % 3
    const size_t ko = (size_t)(t + 2) * BK;
    const bool pf = (t + 2) < NT;
    const bool rd = (t + 1) < NT;

    // ---------------- P0 ----------------
    if (pf) {
      load16_to_lds(Ag1 + ko, &As[nb][ldsO1]);
      load16_to_lds(Ag2 + ko, &As[nb][ldsO2]);
    }
    // part2(t): consumed by P1's cluster; completes under P0's MFMA.
    i32x4 ca4 = *(const i32x4*)&As[buf][offA[4]];
    i32x4 ca5 = *(const i32x4*)&As[buf][offA[5]];
    i32x4 ca6 = *(const i32x4*)&As[buf][offA[6]];
    i32x4 ca7 = *(const i32x4*)&As[buf][offA[7]];
    __builtin_amdgcn_sched_barrier(0);
    __builtin_amdgcn_s_barrier();
    __builtin_amdgcn_sched_barrier(0);
    __builtin_amdgcn_s_setprio(1);
    acc[0][0] = __builtin_amdgcn_mfma_i32_16x16x64_i8(ca0, cb0, acc[0][0], 0, 0, 0);
    acc[0][1] = __builtin_amdgcn_mfma_i32_16x16x64_i8(ca0, cb1, acc[0][1], 0, 0, 0);
    acc[0][2] = __builtin_amdgcn_mfma_i32_16x16x64_i8(ca0, cb2, acc[0][2], 0, 0, 0);
    acc[0][3] = __builtin_amdgcn_mfma_i32_16x16x64_i8(ca0, cb3, acc[0][3], 0, 0, 0);
    acc[1][0] = __builtin_amdgcn_mfma_i32_16x16x64_i8(ca1, cb0, acc[1][0], 0, 0, 0);
    acc[1][1] = __builtin_amdgcn_mfma_i32_16x16x64_i8(ca1, cb1, acc[1][1], 0, 0, 0);
    acc[1][2] = __builtin_amdgcn_mfma_i32_16x16x64_i8(ca1, cb2, acc[1][2], 0, 0, 0);
    acc[1][3] = __builtin_amdgcn_mfma_i32_16x16x64_i8(ca1, cb3, acc[1][3], 0, 0, 0);
    acc[2][0] = __builtin_amdgcn_mfma_i32_16x16x64_i8(ca2, cb0, acc[2][0], 0, 0, 0);
    acc[2][1] = __builtin_amdgcn_mfma_i32_16x16x64_i8(ca2, cb1, acc[2][1], 0, 0, 0);
    acc[2][2] = __builtin_amdgcn_mfma_i32_16x16x64_i8(ca2, cb2, acc[2][2], 0, 0, 0);
    acc[2][3] = __builtin_amdgcn_mfma_i32_16x16x64_i8(ca2, cb3, acc[2][3], 0, 0, 0);
    acc[3][0] = __builtin_amdgcn_mfma_i32_16x16x64_i8(ca3, cb0, acc[3][0], 0, 0, 0);
    acc[3][1] = __builtin_amdgcn_mfma_i32_16x16x64_i8(ca3, cb1, acc[3][1], 0, 0, 0);
    acc[3][2] = __builtin_amdgcn_mfma_i32_16x16x64_i8(ca3, cb2, acc[3][2], 0, 0, 0);
    acc[3][3] = __builtin_amdgcn_mfma_i32_16x16x64_i8(ca3, cb3, acc[3][3], 0, 0, 0);
    __builtin_amdgcn_s_setprio(0);
    __builtin_amdgcn_sched_barrier(0);
    __builtin_amdgcn_s_barrier();
    __builtin_amdgcn_sched_barrier(0);

    // ---------------- P1 ----------------
    if (pf) {
      load16_to_lds(Bg1 + ko, &Bs[nb][ldsO1]);
      load16_to_lds(Bg2 + ko, &Bs[nb][ldsO2]);
    }
    // Retire tile t+1's staging (FIFO: 8 outstanding -> keep newest 4 = tile t+2's).
    if (pf)          { asm volatile("s_waitcnt vmcnt(4)" ::: "memory"); }
    else if (rd)     { asm volatile("s_waitcnt vmcnt(0)" ::: "memory"); }
    // part1(t+1): issued here, consumed by next tile's P0 cluster.
    i32x4 na0 = {}, na1 = {}, na2 = {}, na3 = {};
    i32x4 nb0 = {}, nb1 = {}, nb2 = {}, nb3 = {};
    if (rd) {
      na0 = *(const i32x4*)&As[nx][offA[0]];
      na1 = *(const i32x4*)&As[nx][offA[1]];
      na2 = *(const i32x4*)&As[nx][offA[2]];
      na3 = *(const i32x4*)&As[nx][offA[3]];
      nb0 = *(const i32x4*)&Bs[nx][offB[0]];
      nb1 = *(const i32x4*)&Bs[nx][offB[1]];
      nb2 = *(const i32x4*)&Bs[nx][offB[2]];
      nb3 = *(const i32x4*)&Bs[nx][offB[3]];
    }
    __builtin_amdgcn_sched_barrier(0);
    __builtin_amdgcn_s_barrier();
    __builtin_amdgcn_sched_barrier(0);
    __builtin_amdgcn_s_setprio(1);
    acc[4][0] = __builtin_amdgcn_mfma_i32_16x16x64_i8(ca4, cb0, acc[4][0], 0, 0, 0);
    acc[4][1] = __builtin_amdgcn_mfma_i32_16x16x64_i8(ca4, cb1, acc[4][1], 0, 0, 0);
    acc[4][2] = __builtin_amdgcn_mfma_i32_16x16x64_i8(ca4, cb2, acc[4][2], 0, 0, 0);
    acc[4][3] = __builtin_amdgcn_mfma_i32_16x16x64_i8(ca4, cb3, acc[4][3], 0, 0, 0);
    acc[5][0] = __builtin_amdgcn_mfma_i32_16x16x64_i8(ca5, cb0, acc[5][0], 0, 0, 0);
    acc[5][1] = __builtin_amdgcn_mfma_i32_16x16x64_i8(ca5, cb1, acc[5][1], 0, 0, 0);
    acc[5][2] = __builtin_amdgcn_mfma_i32_16x16x64_i8(ca5, cb2, acc[5][2], 0, 0, 0);
    acc[5][3] = __builtin_amdgcn_mfma_i32_16x16x64_i8(ca5, cb3, acc[5][3], 0, 0, 0);
    acc[6][0] = __builtin_amdgcn_mfma_i32_16x16x64_i8(ca6, cb0, acc[6][0], 0, 0, 0);
    acc[6][1] = __builtin_amdgcn_mfma_i32_16x16x64_i8(ca6, cb1, acc[6][1], 0, 0, 0);
    acc[6][2] = __builtin_amdgcn_mfma_i32_16x16x64_i8(ca6, cb2, acc[6][2], 0, 0, 0);
    acc[6][3] = __builtin_amdgcn_mfma_i32_16x16x64_i8(ca6, cb3, acc[6][3], 0, 0, 0);
    acc[7][0] = __builtin_amdgcn_mfma_i32_16x16x64_i8(ca7, cb0, acc[7][0], 0, 0, 0);
    acc[7][1] = __builtin_amdgcn_mfma_i32_16x16x64_i8(ca7, cb1, acc[7][1], 0, 0, 0);
    acc[7][2] = __builtin_amdgcn_mfma_i32_16x16x64_i8(ca7, cb2, acc[7][2], 0, 0, 0);
    acc[7][3] = __builtin_amdgcn_mfma_i32_16x16x64_i8(ca7, cb3, acc[7][3], 0, 0, 0);
    __builtin_amdgcn_s_setprio(0);
    __builtin_amdgcn_sched_barrier(0);
    __builtin_amdgcn_s_barrier();
    __builtin_amdgcn_sched_barrier(0);

    // rotate part1 regs for next tile
    ca0 = na0; ca1 = na1; ca2 = na2; ca3 = na3;
    cb0 = nb0; cb1 = nb1; cb2 = nb2; cb3 = nb3;
    buf = nx;
  }

  // Epilogue. C/D layout (dtype-independent): col = lane&15, row = (lane>>4)*4 + reg.
  const int colc = lane & 15;
  const int rq   = (lane >> 4) << 2;
  float sxv[8][4];
#pragma unroll
  for (int m = 0; m < 8; ++m) {
    const int row0 = bm * BM + wm * 128 + m * 16 + rq;
#pragma unroll
    for (int r = 0; r < 4; ++r) sxv[m][r] = sx[row0 + r];
  }
#pragma unroll
  for (int n = 0; n < 4; ++n) {
    const int col = bn * BN + wn * 64 + n * 16 + colc;
    const float sc = sw[col];
    const float bi = bias[col];
#pragma unroll
    for (int m = 0; m < 8; ++m) {
      const int row0 = bm * BM + wm * 128 + m * 16 + rq;
#pragma unroll
      for (int r = 0; r < 4; ++r)
        out[(size_t)(row0 + r) * N + col] = (float)acc[m][n][r] * (sxv[m][r] * sc) + bi;
    }
  }
}

extern "C" void kernel_launch(void* const* d_in, const int* in_sizes, int n_in,
                              void* d_out, int out_size, void* d_ws, size_t ws_size,
                              hipStream_t stream) {
  const float* x     = (const float*)d_in[0];
  const int*   w     = (const int*)d_in[1];
  const float* scale = (const float*)d_in[2];
  const float* bias  = (const float*)d_in[3];
  float*       out   = (float*)d_out;

  const int N = in_sizes[3];          // D_OUT = 4096
  const int K = in_sizes[1] / N;      // D_IN  = 4096
  const int M = in_sizes[0] / K;      // B*S   = 8192

  char*  xq = (char*)d_ws;                       // M*K i8  = 32 MiB
  char*  wq = xq + (size_t)M * K;                // N*K i8  = 16 MiB
  float* sx = (float*)(wq + (size_t)N * K);      // M floats

  const unsigned wblocks = (unsigned)(((size_t)N * K) / 4096);
  quant_xw<<<dim3((unsigned)M + wblocks), dim3(256), 0, stream>>>(x, xq, sx, w, wq, M, K);

  gemm_i8_bt<<<dim3(N / BN, M / BM), dim3(512), 0, stream>>>(xq, wq, sx, scale, bias, out, M, N, K);
}

// Round 5
// 416.612 us; speedup vs baseline: 1.1396x; 1.1396x over previous
//
#include <hip/hip_runtime.h>
#include <cstdint>
#include <cstddef>

typedef int i32x4 __attribute__((ext_vector_type(4)));

#define BM 256
#define BN 256
#define BK 64   // bytes of K per tile; one mfma_i32_16x16x64_i8 covers the whole tile-K

__device__ __forceinline__ void load16_to_lds(const void* g, void* l) {
  __builtin_amdgcn_global_load_lds(
      (const __attribute__((address_space(1))) void*)g,
      (__attribute__((address_space(3))) void*)l,
      16, 0, 0);
}

// Fused input quantization.
// Blocks [0, M): per-row absmax + int8 quantize of x (row held in regs).
// Blocks [M, M + N*K/4096): pack int32 weights (values in [-127,127]) to int8.
__global__ __launch_bounds__(256) void quant_xw(const float* __restrict__ x,
                                                char* __restrict__ xq,
                                                float* __restrict__ sx,
                                                const int* __restrict__ w,
                                                char* __restrict__ wq,
                                                int M, int K) {
  const int t = threadIdx.x;
  __shared__ float red[4];
  if ((int)blockIdx.x < M) {
    const int row = blockIdx.x;
    const float* xr = x + (size_t)row * K;
    float4 v[4];
    float amax = 0.f;
#pragma unroll
    for (int j = 0; j < 4; ++j) {
      v[j] = ((const float4*)xr)[t + j * 256];
      amax = fmaxf(amax, fmaxf(fmaxf(fabsf(v[j].x), fabsf(v[j].y)),
                               fmaxf(fabsf(v[j].z), fabsf(v[j].w))));
    }
#pragma unroll
    for (int off = 32; off; off >>= 1)
      amax = fmaxf(amax, __shfl_xor(amax, off));
    if ((t & 63) == 0) red[t >> 6] = amax;
    __syncthreads();
    amax = fmaxf(fmaxf(red[0], red[1]), fmaxf(red[2], red[3]));
    amax = fmaxf(amax, 1e-20f);

    const float s = 127.0f / amax;
    int* outw = (int*)(xq + (size_t)row * K);
#pragma unroll
    for (int j = 0; j < 4; ++j) {
      int q0 = __float2int_rn(v[j].x * s);
      int q1 = __float2int_rn(v[j].y * s);
      int q2 = __float2int_rn(v[j].z * s);
      int q3 = __float2int_rn(v[j].w * s);
      int pk = (q0 & 0xff) | ((q1 & 0xff) << 8) | ((q2 & 0xff) << 16) | ((q3 & 0xff) << 24);
      outw[t + j * 256] = pk;
    }
    if (t == 0) sx[row] = amax * (1.0f / 127.0f);
  } else {
    const size_t base = (size_t)(blockIdx.x - M) * 4096;
    int* outw = (int*)(wq + base);
#pragma unroll
    for (int j = 0; j < 4; ++j) {
      const int c = t + j * 256;
      int4 a = ((const int4*)(w + base))[c];
      outw[c] = (a.x & 0xff) | ((a.y & 0xff) << 8) | ((a.z & 0xff) << 16) | ((a.w & 0xff) << 24);
    }
  }
}

// C[m][n] = sum_k A[m][k]*Bw[n][k] (int8 -> int32); out = C*sx[m]*sw[n] + bias[n].
// 256x256 tile, 1024 thr (16 waves: 4M x 4N -> 64x64 per wave), BK=64B,
// mfma_i32_16x16x64_i8. ROUND-1 SCHEDULE (verified best), occupancy doubled:
// 16 accs/wave (64 AGPR) + ~50 VGPR fits 4 waves/SIMD (vs round-1's 2).
//   P0(t): ds_read a0,a1,b0..b3; stage A(t+2); bar; lgkm0; 8 MFMA; bar
//   P1(t): ds_read a2,a3;        stage B(t+2); bar; lgkm0; 8 MFMA; vmcnt(2); bar
// 3-buffer rotation (tile t in buf t%3; DMA into (t+2)%3 == (t-1)%3, WAR-ordered by
// the tile-final barrier). Counted vmcnt(2): steady-state outstanding
// {A(t+1),B(t+1),A(t+2),B(t+2)} -> retire t+1's pair, keep t+2's in flight.
// LDS swizzle (verified conflict-free): 16B chunk (row r, chunk c) at byte
// r*64 + ((c^((r>>1)&3))<<4); staged via pre-swizzled global source, linear DMA dst.
__global__ __launch_bounds__(1024) void gemm_i8_bt(const char* __restrict__ A,
                                                   const char* __restrict__ Bw,
                                                   const float* __restrict__ sx,
                                                   const float* __restrict__ sw,
                                                   const float* __restrict__ bias,
                                                   float* __restrict__ out,
                                                   int M, int N, int K) {
  __shared__ __align__(16) char As[3][BM * BK];   // 3 x 16 KiB
  __shared__ __align__(16) char Bs[3][BN * BK];   // 3 x 16 KiB  (96 KiB total)

  const int tid  = threadIdx.x;
  const int wave = tid >> 6;
  const int lane = tid & 63;
  const int wm   = wave >> 2;      // 0..3 -> 64-row block
  const int wn   = wave & 3;       // 0..3 -> 64-col block

  // XCD-aware bijective block swizzle (nwg = 512, divisible by 8)
  const int gx   = N / BN;                              // 16
  const int nwg  = gx * (M / BM);                       // 512
  const int orig = blockIdx.y * gx + blockIdx.x;
  const int wg   = (orig & 7) * (nwg >> 3) + (orig >> 3);
  const int bn   = wg % gx;
  const int bm   = wg / gx;

  i32x4 acc[4][4] = {};

  // Staging: thread stages 16B chunk q=tid of each tile (1024 x 16B = 16 KiB).
  // LDS chunk position p=q&3 of row q>>2 holds global chunk p ^ ((row>>1)&3).
  const int rowT = tid >> 2;
  const int jg   = ((tid & 3) ^ ((tid >> 3) & 3)) << 4;
  const char* Ag = A  + (size_t)(bm * BM + rowT) * K + jg;
  const char* Bg = Bw + (size_t)(bn * BN + rowT) * K + jg;

  const int ldsO = wave << 10;    // chunk q=tid -> byte tid*16 (wave-uniform base)

  // Fragment read offsets: row R, k-chunk j=lane>>4 at byte R*64 + ((j^((R>>1)&3))<<4).
  // ((R>>1)&3) == ((fr>>1)&3): wm*64 and m*16 are 0 mod 16.
  const int fr  = lane & 15;
  const int swz = (((lane >> 4) ^ ((fr >> 1) & 3)) << 4);
  int offA[4], offB[4];
#pragma unroll
  for (int m = 0; m < 4; ++m) offA[m] = (wm * 64 + m * 16 + fr) * 64 + swz;
#pragma unroll
  for (int n = 0; n < 4; ++n) offB[n] = (wn * 64 + n * 16 + fr) * 64 + swz;

  const int NT = K / BK;    // 64

  // Prologue: stage tiles 0,1; retire tile 0's pair (keep tile 1's in flight).
  load16_to_lds(Ag,      &As[0][ldsO]);
  load16_to_lds(Bg,      &Bs[0][ldsO]);
  load16_to_lds(Ag + BK, &As[1][ldsO]);
  load16_to_lds(Bg + BK, &Bs[1][ldsO]);
  asm volatile("s_waitcnt vmcnt(2)" ::: "memory");
  __builtin_amdgcn_s_barrier();

  int buf = 0;                              // tile t lives in buffer t % 3
  for (int t = 0; t < NT; ++t) {
    const int  nb = (buf >= 1) ? buf - 1 : 2;      // (t+2) % 3
    const size_t ko = (size_t)(t + 2) * BK;
    const bool pf = (t + 2) < NT;
    const bool rd = (t + 1) < NT;

    // ---------------- P0: a0,a1 x b0..b3 ----------------
    i32x4 a0 = *(const i32x4*)&As[buf][offA[0]];
    i32x4 a1 = *(const i32x4*)&As[buf][offA[1]];
    i32x4 b0 = *(const i32x4*)&Bs[buf][offB[0]];
    i32x4 b1 = *(const i32x4*)&Bs[buf][offB[1]];
    i32x4 b2 = *(const i32x4*)&Bs[buf][offB[2]];
    i32x4 b3 = *(const i32x4*)&Bs[buf][offB[3]];
    if (pf) load16_to_lds(Ag + ko, &As[nb][ldsO]);
    __builtin_amdgcn_s_barrier();
    asm volatile("s_waitcnt lgkmcnt(0)" ::: "memory");
    __builtin_amdgcn_sched_barrier(0);
    __builtin_amdgcn_s_setprio(1);
    acc[0][0] = __builtin_amdgcn_mfma_i32_16x16x64_i8(a0, b0, acc[0][0], 0, 0, 0);
    acc[0][1] = __builtin_amdgcn_mfma_i32_16x16x64_i8(a0, b1, acc[0][1], 0, 0, 0);
    acc[0][2] = __builtin_amdgcn_mfma_i32_16x16x64_i8(a0, b2, acc[0][2], 0, 0, 0);
    acc[0][3] = __builtin_amdgcn_mfma_i32_16x16x64_i8(a0, b3, acc[0][3], 0, 0, 0);
    acc[1][0] = __builtin_amdgcn_mfma_i32_16x16x64_i8(a1, b0, acc[1][0], 0, 0, 0);
    acc[1][1] = __builtin_amdgcn_mfma_i32_16x16x64_i8(a1, b1, acc[1][1], 0, 0, 0);
    acc[1][2] = __builtin_amdgcn_mfma_i32_16x16x64_i8(a1, b2, acc[1][2], 0, 0, 0);
    acc[1][3] = __builtin_amdgcn_mfma_i32_16x16x64_i8(a1, b3, acc[1][3], 0, 0, 0);
    __builtin_amdgcn_s_setprio(0);
    __builtin_amdgcn_s_barrier();

    // ---------------- P1: a2,a3 x b0..b3 ----------------
    i32x4 a2 = *(const i32x4*)&As[buf][offA[2]];
    i32x4 a3 = *(const i32x4*)&As[buf][offA[3]];
    if (pf) load16_to_lds(Bg + ko, &Bs[nb][ldsO]);
    __builtin_amdgcn_s_barrier();
    asm volatile("s_waitcnt lgkmcnt(0)" ::: "memory");
    __builtin_amdgcn_sched_barrier(0);
    __builtin_amdgcn_s_setprio(1);
    acc[2][0] = __builtin_amdgcn_mfma_i32_16x16x64_i8(a2, b0, acc[2][0], 0, 0, 0);
    acc[2][1] = __builtin_amdgcn_mfma_i32_16x16x64_i8(a2, b1, acc[2][1], 0, 0, 0);
    acc[2][2] = __builtin_amdgcn_mfma_i32_16x16x64_i8(a2, b2, acc[2][2], 0, 0, 0);
    acc[2][3] = __builtin_amdgcn_mfma_i32_16x16x64_i8(a2, b3, acc[2][3], 0, 0, 0);
    acc[3][0] = __builtin_amdgcn_mfma_i32_16x16x64_i8(a3, b0, acc[3][0], 0, 0, 0);
    acc[3][1] = __builtin_amdgcn_mfma_i32_16x16x64_i8(a3, b1, acc[3][1], 0, 0, 0);
    acc[3][2] = __builtin_amdgcn_mfma_i32_16x16x64_i8(a3, b2, acc[3][2], 0, 0, 0);
    acc[3][3] = __builtin_amdgcn_mfma_i32_16x16x64_i8(a3, b3, acc[3][3], 0, 0, 0);
    __builtin_amdgcn_s_setprio(0);

    // Tile boundary: retire tile t+1's 2 loads, keep tile t+2's 2 in flight.
    if (pf)          { asm volatile("s_waitcnt vmcnt(2)" ::: "memory"); }
    else if (rd)     { asm volatile("s_waitcnt vmcnt(0)" ::: "memory"); }
    __builtin_amdgcn_s_barrier();

    buf = (buf < 2) ? buf + 1 : 0;
  }

  // Epilogue. C/D layout (dtype-independent): col = lane&15, row = (lane>>4)*4 + reg.
  const int colc = lane & 15;
  const int rq   = (lane >> 4) << 2;
  float sxv[4][4];
#pragma unroll
  for (int m = 0; m < 4; ++m) {
    const int row0 = bm * BM + wm * 64 + m * 16 + rq;
#pragma unroll
    for (int r = 0; r < 4; ++r) sxv[m][r] = sx[row0 + r];
  }
#pragma unroll
  for (int n = 0; n < 4; ++n) {
    const int col = bn * BN + wn * 64 + n * 16 + colc;
    const float sc = sw[col];
    const float bi = bias[col];
#pragma unroll
    for (int m = 0; m < 4; ++m) {
      const int row0 = bm * BM + wm * 64 + m * 16 + rq;
#pragma unroll
      for (int r = 0; r < 4; ++r)
        out[(size_t)(row0 + r) * N + col] = (float)acc[m][n][r] * (sxv[m][r] * sc) + bi;
    }
  }
}

extern "C" void kernel_launch(void* const* d_in, const int* in_sizes, int n_in,
                              void* d_out, int out_size, void* d_ws, size_t ws_size,
                              hipStream_t stream) {
  const float* x     = (const float*)d_in[0];
  const int*   w     = (const int*)d_in[1];
  const float* scale = (const float*)d_in[2];
  const float* bias  = (const float*)d_in[3];
  float*       out   = (float*)d_out;

  const int N = in_sizes[3];          // D_OUT = 4096
  const int K = in_sizes[1] / N;      // D_IN  = 4096
  const int M = in_sizes[0] / K;      // B*S   = 8192

  char*  xq = (char*)d_ws;                       // M*K i8  = 32 MiB
  char*  wq = xq + (size_t)M * K;                // N*K i8  = 16 MiB
  float* sx = (float*)(wq + (size_t)N * K);      // M floats

  const unsigned wblocks = (unsigned)(((size_t)N * K) / 4096);
  quant_xw<<<dim3((unsigned)M + wblocks), dim3(256), 0, stream>>>(x, xq, sx, w, wq, M, K);

  gemm_i8_bt<<<dim3(N / BN, M / BM), dim3(1024), 0, stream>>>(xq, wq, sx, scale, bias, out, M, N, K);
}

// Round 6
// 411.888 us; speedup vs baseline: 1.1526x; 1.0115x over previous
//
#include <hip/hip_runtime.h>
#include <cstdint>
#include <cstddef>

typedef int i32x4 __attribute__((ext_vector_type(4)));

#define BM 256
#define BN 256
#define BK 64   // bytes of K per tile; one mfma_i32_16x16x64_i8 covers the whole tile-K

__device__ __forceinline__ void load16_to_lds(const void* g, void* l) {
  __builtin_amdgcn_global_load_lds(
      (const __attribute__((address_space(1))) void*)g,
      (__attribute__((address_space(3))) void*)l,
      16, 0, 0);
}

// Fused input quantization, one WAVE per row, no barriers / no LDS:
// wave-task id wid in [0, M):          per-row absmax + int8 quantize of x.
// wid in [M, M+N):                     pack one int32 weight row to int8.
// Lane l covers elements {j*64+l : j=0..15} (float4/int4 granules) -> all loads and
// stores coalesced per instruction; 16 loads in flight before the reduce dependency.
__global__ __launch_bounds__(256) void quant_xw(const float* __restrict__ x,
                                                char* __restrict__ xq,
                                                float* __restrict__ sx,
                                                const int* __restrict__ w,
                                                char* __restrict__ wq,
                                                int M, int K) {
  const int wid = blockIdx.x * 4 + (threadIdx.x >> 6);
  const int l   = threadIdx.x & 63;
  if (wid < M) {
    const float4* xr = (const float4*)(x + (size_t)wid * K);
    float4 v[16];
    float amax = 0.f;
#pragma unroll
    for (int j = 0; j < 16; ++j) {
      v[j] = xr[j * 64 + l];
      amax = fmaxf(amax, fmaxf(fmaxf(fabsf(v[j].x), fabsf(v[j].y)),
                               fmaxf(fabsf(v[j].z), fabsf(v[j].w))));
    }
#pragma unroll
    for (int off = 32; off; off >>= 1)
      amax = fmaxf(amax, __shfl_xor(amax, off));
    amax = fmaxf(amax, 1e-20f);

    const float s = 127.0f / amax;
    int* outw = (int*)(xq + (size_t)wid * K);
#pragma unroll
    for (int j = 0; j < 16; ++j) {
      int q0 = __float2int_rn(v[j].x * s);
      int q1 = __float2int_rn(v[j].y * s);
      int q2 = __float2int_rn(v[j].z * s);
      int q3 = __float2int_rn(v[j].w * s);
      outw[j * 64 + l] = (q0 & 0xff) | ((q1 & 0xff) << 8) |
                         ((q2 & 0xff) << 16) | ((q3 & 0xff) << 24);
    }
    if (l == 0) sx[wid] = amax * (1.0f / 127.0f);
  } else {
    const int r = wid - M;
    const int4* wr = (const int4*)(w + (size_t)r * K);
    int* outw = (int*)(wq + (size_t)r * K);
#pragma unroll
    for (int j = 0; j < 16; ++j) {
      int4 a = wr[j * 64 + l];
      outw[j * 64 + l] = (a.x & 0xff) | ((a.y & 0xff) << 8) |
                         ((a.z & 0xff) << 16) | ((a.w & 0xff) << 24);
    }
  }
}

// C[m][n] = sum_k A[m][k]*Bw[n][k] (int8 -> int32); out = C*sx[m]*sw[n] + bias[n].
// 256x256 tile, 1024 thr (16 waves: 4M x 4N -> 64x64 per wave), BK=64B,
// mfma_i32_16x16x64_i8. ROUND-5 SCHEDULE, VERIFIED BEST — DO NOT MODIFY.
//   P0(t): ds_read a0,a1,b0..b3; stage A(t+2); bar; lgkm0; 8 MFMA; bar
//   P1(t): ds_read a2,a3;        stage B(t+2); bar; lgkm0; 8 MFMA; vmcnt(2); bar
// 3-buffer rotation (tile t in buf t%3; DMA into (t+2)%3 == (t-1)%3, WAR-ordered by
// the tile-final barrier). Counted vmcnt(2): steady-state outstanding
// {A(t+1),B(t+1),A(t+2),B(t+2)} -> retire t+1's pair, keep t+2's in flight.
// LDS swizzle (verified conflict-free): 16B chunk (row r, chunk c) at byte
// r*64 + ((c^((r>>1)&3))<<4); staged via pre-swizzled global source, linear DMA dst.
__global__ __launch_bounds__(1024) void gemm_i8_bt(const char* __restrict__ A,
                                                   const char* __restrict__ Bw,
                                                   const float* __restrict__ sx,
                                                   const float* __restrict__ sw,
                                                   const float* __restrict__ bias,
                                                   float* __restrict__ out,
                                                   int M, int N, int K) {
  __shared__ __align__(16) char As[3][BM * BK];   // 3 x 16 KiB
  __shared__ __align__(16) char Bs[3][BN * BK];   // 3 x 16 KiB  (96 KiB total)

  const int tid  = threadIdx.x;
  const int wave = tid >> 6;
  const int lane = tid & 63;
  const int wm   = wave >> 2;      // 0..3 -> 64-row block
  const int wn   = wave & 3;       // 0..3 -> 64-col block

  // XCD-aware bijective block swizzle (nwg = 512, divisible by 8)
  const int gx   = N / BN;                              // 16
  const int nwg  = gx * (M / BM);                       // 512
  const int orig = blockIdx.y * gx + blockIdx.x;
  const int wg   = (orig & 7) * (nwg >> 3) + (orig >> 3);
  const int bn   = wg % gx;
  const int bm   = wg / gx;

  i32x4 acc[4][4] = {};

  // Staging: thread stages 16B chunk q=tid of each tile (1024 x 16B = 16 KiB).
  // LDS chunk position p=q&3 of row q>>2 holds global chunk p ^ ((row>>1)&3).
  const int rowT = tid >> 2;
  const int jg   = ((tid & 3) ^ ((tid >> 3) & 3)) << 4;
  const char* Ag = A  + (size_t)(bm * BM + rowT) * K + jg;
  const char* Bg = Bw + (size_t)(bn * BN + rowT) * K + jg;

  const int ldsO = wave << 10;    // chunk q=tid -> byte tid*16 (wave-uniform base)

  // Fragment read offsets: row R, k-chunk j=lane>>4 at byte R*64 + ((j^((R>>1)&3))<<4).
  // ((R>>1)&3) == ((fr>>1)&3): wm*64 and m*16 are 0 mod 16.
  const int fr  = lane & 15;
  const int swz = (((lane >> 4) ^ ((fr >> 1) & 3)) << 4);
  int offA[4], offB[4];
#pragma unroll
  for (int m = 0; m < 4; ++m) offA[m] = (wm * 64 + m * 16 + fr) * 64 + swz;
#pragma unroll
  for (int n = 0; n < 4; ++n) offB[n] = (wn * 64 + n * 16 + fr) * 64 + swz;

  const int NT = K / BK;    // 64

  // Prologue: stage tiles 0,1; retire tile 0's pair (keep tile 1's in flight).
  load16_to_lds(Ag,      &As[0][ldsO]);
  load16_to_lds(Bg,      &Bs[0][ldsO]);
  load16_to_lds(Ag + BK, &As[1][ldsO]);
  load16_to_lds(Bg + BK, &Bs[1][ldsO]);
  asm volatile("s_waitcnt vmcnt(2)" ::: "memory");
  __builtin_amdgcn_s_barrier();

  int buf = 0;                              // tile t lives in buffer t % 3
  for (int t = 0; t < NT; ++t) {
    const int  nb = (buf >= 1) ? buf - 1 : 2;      // (t+2) % 3
    const size_t ko = (size_t)(t + 2) * BK;
    const bool pf = (t + 2) < NT;
    const bool rd = (t + 1) < NT;

    // ---------------- P0: a0,a1 x b0..b3 ----------------
    i32x4 a0 = *(const i32x4*)&As[buf][offA[0]];
    i32x4 a1 = *(const i32x4*)&As[buf][offA[1]];
    i32x4 b0 = *(const i32x4*)&Bs[buf][offB[0]];
    i32x4 b1 = *(const i32x4*)&Bs[buf][offB[1]];
    i32x4 b2 = *(const i32x4*)&Bs[buf][offB[2]];
    i32x4 b3 = *(const i32x4*)&Bs[buf][offB[3]];
    if (pf) load16_to_lds(Ag + ko, &As[nb][ldsO]);
    __builtin_amdgcn_s_barrier();
    asm volatile("s_waitcnt lgkmcnt(0)" ::: "memory");
    __builtin_amdgcn_sched_barrier(0);
    __builtin_amdgcn_s_setprio(1);
    acc[0][0] = __builtin_amdgcn_mfma_i32_16x16x64_i8(a0, b0, acc[0][0], 0, 0, 0);
    acc[0][1] = __builtin_amdgcn_mfma_i32_16x16x64_i8(a0, b1, acc[0][1], 0, 0, 0);
    acc[0][2] = __builtin_amdgcn_mfma_i32_16x16x64_i8(a0, b2, acc[0][2], 0, 0, 0);
    acc[0][3] = __builtin_amdgcn_mfma_i32_16x16x64_i8(a0, b3, acc[0][3], 0, 0, 0);
    acc[1][0] = __builtin_amdgcn_mfma_i32_16x16x64_i8(a1, b0, acc[1][0], 0, 0, 0);
    acc[1][1] = __builtin_amdgcn_mfma_i32_16x16x64_i8(a1, b1, acc[1][1], 0, 0, 0);
    acc[1][2] = __builtin_amdgcn_mfma_i32_16x16x64_i8(a1, b2, acc[1][2], 0, 0, 0);
    acc[1][3] = __builtin_amdgcn_mfma_i32_16x16x64_i8(a1, b3, acc[1][3], 0, 0, 0);
    __builtin_amdgcn_s_setprio(0);
    __builtin_amdgcn_s_barrier();

    // ---------------- P1: a2,a3 x b0..b3 ----------------
    i32x4 a2 = *(const i32x4*)&As[buf][offA[2]];
    i32x4 a3 = *(const i32x4*)&As[buf][offA[3]];
    if (pf) load16_to_lds(Bg + ko, &Bs[nb][ldsO]);
    __builtin_amdgcn_s_barrier();
    asm volatile("s_waitcnt lgkmcnt(0)" ::: "memory");
    __builtin_amdgcn_sched_barrier(0);
    __builtin_amdgcn_s_setprio(1);
    acc[2][0] = __builtin_amdgcn_mfma_i32_16x16x64_i8(a2, b0, acc[2][0], 0, 0, 0);
    acc[2][1] = __builtin_amdgcn_mfma_i32_16x16x64_i8(a2, b1, acc[2][1], 0, 0, 0);
    acc[2][2] = __builtin_amdgcn_mfma_i32_16x16x64_i8(a2, b2, acc[2][2], 0, 0, 0);
    acc[2][3] = __builtin_amdgcn_mfma_i32_16x16x64_i8(a2, b3, acc[2][3], 0, 0, 0);
    acc[3][0] = __builtin_amdgcn_mfma_i32_16x16x64_i8(a3, b0, acc[3][0], 0, 0, 0);
    acc[3][1] = __builtin_amdgcn_mfma_i32_16x16x64_i8(a3, b1, acc[3][1], 0, 0, 0);
    acc[3][2] = __builtin_amdgcn_mfma_i32_16x16x64_i8(a3, b2, acc[3][2], 0, 0, 0);
    acc[3][3] = __builtin_amdgcn_mfma_i32_16x16x64_i8(a3, b3, acc[3][3], 0, 0, 0);
    __builtin_amdgcn_s_setprio(0);

    // Tile boundary: retire tile t+1's 2 loads, keep tile t+2's 2 in flight.
    if (pf)          { asm volatile("s_waitcnt vmcnt(2)" ::: "memory"); }
    else if (rd)     { asm volatile("s_waitcnt vmcnt(0)" ::: "memory"); }
    __builtin_amdgcn_s_barrier();

    buf = (buf < 2) ? buf + 1 : 0;
  }

  // Epilogue. C/D layout (dtype-independent): col = lane&15, row = (lane>>4)*4 + reg.
  const int colc = lane & 15;
  const int rq   = (lane >> 4) << 2;
  float sxv[4][4];
#pragma unroll
  for (int m = 0; m < 4; ++m) {
    const int row0 = bm * BM + wm * 64 + m * 16 + rq;
#pragma unroll
    for (int r = 0; r < 4; ++r) sxv[m][r] = sx[row0 + r];
  }
#pragma unroll
  for (int n = 0; n < 4; ++n) {
    const int col = bn * BN + wn * 64 + n * 16 + colc;
    const float sc = sw[col];
    const float bi = bias[col];
#pragma unroll
    for (int m = 0; m < 4; ++m) {
      const int row0 = bm * BM + wm * 64 + m * 16 + rq;
#pragma unroll
      for (int r = 0; r < 4; ++r)
        out[(size_t)(row0 + r) * N + col] = (float)acc[m][n][r] * (sxv[m][r] * sc) + bi;
    }
  }
}

extern "C" void kernel_launch(void* const* d_in, const int* in_sizes, int n_in,
                              void* d_out, int out_size, void* d_ws, size_t ws_size,
                              hipStream_t stream) {
  const float* x     = (const float*)d_in[0];
  const int*   w     = (const int*)d_in[1];
  const float* scale = (const float*)d_in[2];
  const float* bias  = (const float*)d_in[3];
  float*       out   = (float*)d_out;

  const int N = in_sizes[3];          // D_OUT = 4096
  const int K = in_sizes[1] / N;      // D_IN  = 4096
  const int M = in_sizes[0] / K;      // B*S   = 8192

  char*  xq = (char*)d_ws;                       // M*K i8  = 32 MiB
  char*  wq = xq + (size_t)M * K;                // N*K i8  = 16 MiB
  float* sx = (float*)(wq + (size_t)N * K);      // M floats

  // Wave-tasks: M x-rows + N w-rows; 4 waves per 256-thr block.
  const unsigned nwaves = (unsigned)(M + N);
  quant_xw<<<dim3(nwaves / 4), dim3(256), 0, stream>>>(x, xq, sx, w, wq, M, K);

  gemm_i8_bt<<<dim3(N / BN, M / BM), dim3(1024), 0, stream>>>(xq, wq, sx, scale, bias, out, M, N, K);
}